// Round 3
// baseline (542.478 us; speedup 1.0000x reference)
//
#include <hip/hip_runtime.h>
#include <stdint.h>

#define SEQ   2048
#define BATCH 4
#define NH    16
#define HD    64
#define HID   1024
#define NPOS  73

typedef __attribute__((ext_vector_type(8))) short short8;
typedef __attribute__((ext_vector_type(4))) short short4v;
typedef __attribute__((ext_vector_type(4))) float f32x4;

static __device__ __forceinline__ float bf2f(short s) {
  return __uint_as_float(((unsigned)(unsigned short)s) << 16);
}
static __device__ __forceinline__ short f2bf(float f) {
  unsigned u = __float_as_uint(f);
  u += 0x7fffu + ((u >> 16) & 1u);
  return (short)(u >> 16);
}

static __device__ __forceinline__ void gload_lds16(const void* g, void* lds) {
  __builtin_amdgcn_global_load_lds(
      (const __attribute__((address_space(1))) unsigned int*)g,
      (__attribute__((address_space(3))) unsigned int*)lds, 16, 0, 0);
}

__global__ __launch_bounds__(256) void cvt_kernel(const float* __restrict__ in,
                                                  short* __restrict__ out, int n4) {
  int i = blockIdx.x * 256 + threadIdx.x;
  if (i >= n4) return;
  f32x4 f = *(const f32x4*)(in + (long)i * 4);
  short4v o;
  o[0] = f2bf(f[0]); o[1] = f2bf(f[1]); o[2] = f2bf(f[2]); o[3] = f2bf(f[3]);
  *(short4v*)(out + (long)i * 4) = o;
}

// C = A * B^T + bias. A:[M,K] bf16 row-major, B:[N,K] bf16 row-major (NT).
// MODE 0: bf16 out scattered to [b,h,l,d] (row->(b,l), col->(h,d)), (acc+bias)*scale
// MODE 1: fp32 out [M,HID] row-major
template <int MODE>
__global__ __launch_bounds__(256) void gemm_nt(const short* __restrict__ A,
                                               const short* __restrict__ B,
                                               const float* __restrict__ bias,
                                               void* __restrict__ Cout, float scale) {
  __shared__ __align__(16) short As[128 * 32];
  __shared__ __align__(16) short Bs[128 * 32];
  const int K = HID;
  const f32x4 fzero = {0.f, 0.f, 0.f, 0.f};
  int t = threadIdx.x;
  int w = t >> 6, lane = t & 63;
  int wr = w >> 1, wc = w & 1;
  int g = lane >> 4, r = lane & 15;
  long tile_m = (long)blockIdx.x * 128;
  long tile_n = (long)blockIdx.y * 128;

  f32x4 acc[4][4];
#pragma unroll
  for (int m = 0; m < 4; ++m)
#pragma unroll
    for (int n = 0; n < 4; ++n) acc[m][n] = fzero;

  // staging: each wave fills chunks 2w,2w+1 of the 8KB tile; lds dst = base + lane*16B
  int e0 = w * 1024 + lane * 8;
  int e1 = e0 + 512;
  const short* A0 = A + (tile_m + (e0 >> 5)) * K + (e0 & 31);
  const short* A1 = A + (tile_m + (e1 >> 5)) * K + (e1 & 31);
  const short* B0 = B + (tile_n + (e0 >> 5)) * K + (e0 & 31);
  const short* B1 = B + (tile_n + (e1 >> 5)) * K + (e1 & 31);

  for (int k0 = 0; k0 < K; k0 += 32) {
    __syncthreads();
    gload_lds16(A0 + k0, &As[e0]);
    gload_lds16(A1 + k0, &As[e1]);
    gload_lds16(B0 + k0, &Bs[e0]);
    gload_lds16(B1 + k0, &Bs[e1]);
    __syncthreads();
    short8 af[4], bfr[4];
#pragma unroll
    for (int m = 0; m < 4; ++m)
      af[m] = *(const short8*)&As[(wr * 64 + m * 16 + r) * 32 + g * 8];
#pragma unroll
    for (int n = 0; n < 4; ++n)
      bfr[n] = *(const short8*)&Bs[(wc * 64 + n * 16 + r) * 32 + g * 8];
#pragma unroll
    for (int m = 0; m < 4; ++m)
#pragma unroll
      for (int n = 0; n < 4; ++n)
        acc[m][n] = __builtin_amdgcn_mfma_f32_16x16x32_bf16(af[m], bfr[n], acc[m][n], 0, 0, 0);
  }

#pragma unroll
  for (int m = 0; m < 4; ++m) {
    int row0 = (int)tile_m + wr * 64 + m * 16 + g * 4;
#pragma unroll
    for (int n = 0; n < 4; ++n) {
      int col = (int)tile_n + wc * 64 + n * 16 + r;
      float bs = bias[col];
#pragma unroll
      for (int j = 0; j < 4; ++j) {
        int row = row0 + j;
        float val = (acc[m][n][j] + bs) * scale;
        if (MODE == 0) {
          int b = row >> 11, l = row & (SEQ - 1);
          int hh = col >> 6, d = col & 63;
          ((short*)Cout)[(((long)(b * NH + hh) * SEQ + l) << 6) + d] = f2bf(val);
        } else {
          ((float*)Cout)[(long)row * HID + col] = val;
        }
      }
    }
  }
}

// Flash attention with relative-position bias.
// grid (SEQ/64, NH, BATCH), 256 threads. Q pre-scaled by 1/sqrt(HD).
__global__ __launch_bounds__(256) void attn_kernel(const short* __restrict__ Qg,
                                                   const short* __restrict__ Kg,
                                                   const short* __restrict__ Vg,
                                                   const short* __restrict__ DE,
                                                   short* __restrict__ ctx) {
  __shared__ __align__(16) short Qs[64 * 64];
  __shared__ __align__(16) short Ks[64 * 64];
  __shared__ __align__(16) short Vt[64 * 64];   // V transposed [d][key]
  __shared__ __align__(16) short Ds[NPOS * 64];
  __shared__ float qd[64 * NPOS];               // per-row dist-bias dot products
  __shared__ __align__(16) short Pb[4][16 * 64];

  const f32x4 fzero = {0.f, 0.f, 0.f, 0.f};
  int t = threadIdx.x;
  int w = t >> 6, lane = t & 63;
  int g = lane >> 4, r = lane & 15;
  int qt = blockIdx.x, h = blockIdx.y, b = blockIdx.z;
  int q0 = qt * 64;
  const short* Qp = Qg + ((long)(b * NH + h) * SEQ + q0) * HD;
  const short* Kp = Kg + (long)(b * NH + h) * SEQ * HD;
  const short* Vp = Vg + (long)(b * NH + h) * SEQ * HD;

  // stage Q tile (contiguous 4096 elems) + dist_emb (4672 elems)
  int e0 = w * 1024 + lane * 8;
  int e1 = e0 + 512;
  gload_lds16(Qp + e0, &Qs[e0]);
  gload_lds16(Qp + e1, &Qs[e1]);
#pragma unroll
  for (int i = 0; i < 3; ++i) {
    int e = i * 2048 + t * 8;
    if (e < NPOS * 64) gload_lds16(DE + e, &Ds[e]);
  }
  __syncthreads();

  // qd[row][p] = sum_d Q[row][d] * dist_emb[p][d]  (scale already in Q)
  for (int idx = t; idx < 64 * NPOS; idx += 256) {
    int row = idx / NPOS, p = idx - row * NPOS;
    float s = 0.f;
#pragma unroll
    for (int d0 = 0; d0 < 64; d0 += 8) {
      short8 a = *(const short8*)&Qs[row * 64 + d0];
      short8 bb = *(const short8*)&Ds[p * 64 + d0];
#pragma unroll
      for (int j = 0; j < 8; ++j) s += bf2f(a[j]) * bf2f(bb[j]);
    }
    qd[idx] = s;
  }

  // hoist Q A-fragments (wave w owns rows w*16..w*16+15)
  short8 aq[2];
#pragma unroll
  for (int kb = 0; kb < 2; ++kb)
    aq[kb] = *(const short8*)&Qs[(w * 16 + r) * 64 + kb * 32 + g * 8];

  f32x4 o[4];
#pragma unroll
  for (int n = 0; n < 4; ++n) o[n] = fzero;
  float mrow[4] = {-1e30f, -1e30f, -1e30f, -1e30f};
  float lrow[4] = {0.f, 0.f, 0.f, 0.f};

  int vr = t >> 2, vc0 = (t & 3) * 16;
  int rowl = w * 16 + g * 4;

  for (int kt = 0; kt < 32; ++kt) {
    int kv0 = kt * 64;
    __syncthreads();  // prior tile's LDS reads done (also orders qd writes->reads at kt=0)
    gload_lds16(Kp + (long)kv0 * HD + e0, &Ks[e0]);
    gload_lds16(Kp + (long)kv0 * HD + e1, &Ks[e1]);
    {  // V transpose staging: thread reads 16 elems of a V row, writes Vt columns
      const short* vp = Vp + (long)(kv0 + vr) * HD + vc0;
      short8 v0 = *(const short8*)vp;
      short8 v1 = *(const short8*)(vp + 8);
#pragma unroll
      for (int jj = 0; jj < 8; ++jj) Vt[(vc0 + jj) * 64 + vr] = v0[jj];
#pragma unroll
      for (int jj = 0; jj < 8; ++jj) Vt[(vc0 + 8 + jj) * 64 + vr] = v1[jj];
    }
    __syncthreads();

    // S = Q K^T   (16 rows x 64 keys per wave)
    f32x4 s[4];
#pragma unroll
    for (int n = 0; n < 4; ++n) s[n] = fzero;
#pragma unroll
    for (int kb = 0; kb < 2; ++kb)
#pragma unroll
      for (int n = 0; n < 4; ++n) {
        short8 bfr = *(const short8*)&Ks[(n * 16 + r) * 64 + kb * 32 + g * 8];
        s[n] = __builtin_amdgcn_mfma_f32_16x16x32_bf16(aq[kb], bfr, s[n], 0, 0, 0);
      }

    // add relative bias, find row max
    float pm[4] = {-1e30f, -1e30f, -1e30f, -1e30f};
#pragma unroll
    for (int n = 0; n < 4; ++n) {
      int cg = kv0 + n * 16 + r;  // global key index
#pragma unroll
      for (int j = 0; j < 4; ++j) {
        int lq = q0 + rowl + j;
        int dist = cg - lq;
        dist = dist < -64 ? -64 : (dist > 8 ? 8 : dist);
        float val = s[n][j] + qd[(rowl + j) * NPOS + dist + 64];
        s[n][j] = val;
        pm[j] = fmaxf(pm[j], val);
      }
    }
#pragma unroll
    for (int off = 1; off < 16; off <<= 1)
#pragma unroll
      for (int j = 0; j < 4; ++j) pm[j] = fmaxf(pm[j], __shfl_xor(pm[j], off));

#pragma unroll
    for (int j = 0; j < 4; ++j) {
      float mn = fmaxf(mrow[j], pm[j]);
      float corr = __expf(mrow[j] - mn);
      mrow[j] = mn;
      lrow[j] *= corr;
#pragma unroll
      for (int n = 0; n < 4; ++n) o[n][j] *= corr;
    }
#pragma unroll
    for (int n = 0; n < 4; ++n)
#pragma unroll
      for (int j = 0; j < 4; ++j) {
        float p = __expf(s[n][j] - mrow[j]);
        lrow[j] += p;  // per-lane partial; reduced at end
        Pb[w][(g * 4 + j) * 64 + n * 16 + r] = f2bf(p);
      }

    // O += P V   (same-wave LDS RAW: DS ops are in-order per wave)
#pragma unroll
    for (int kb = 0; kb < 2; ++kb) {
      short8 pa = *(const short8*)&Pb[w][r * 64 + kb * 32 + g * 8];
#pragma unroll
      for (int n = 0; n < 4; ++n) {
        short8 vb = *(const short8*)&Vt[(n * 16 + r) * 64 + kb * 32 + g * 8];
        o[n] = __builtin_amdgcn_mfma_f32_16x16x32_bf16(pa, vb, o[n], 0, 0, 0);
      }
    }
  }

#pragma unroll
  for (int off = 1; off < 16; off <<= 1)
#pragma unroll
    for (int j = 0; j < 4; ++j) lrow[j] += __shfl_xor(lrow[j], off);

#pragma unroll
  for (int n = 0; n < 4; ++n)
#pragma unroll
    for (int j = 0; j < 4; ++j) {
      int grow = b * SEQ + q0 + rowl + j;
      int gcol = h * HD + n * 16 + r;
      ctx[(long)grow * HID + gcol] = f2bf(o[n][j] / lrow[j]);
    }
}

extern "C" void kernel_launch(void* const* d_in, const int* in_sizes, int n_in,
                              void* d_out, int out_size, void* d_ws, size_t ws_size,
                              hipStream_t stream) {
  if (n_in < 10) return;
  const float* hs = (const float*)d_in[0];
  const float* Wq = (const float*)d_in[1];
  const float* bq = (const float*)d_in[2];
  const float* Wk = (const float*)d_in[3];
  const float* bk = (const float*)d_in[4];
  const float* Wv = (const float*)d_in[5];
  const float* bv = (const float*)d_in[6];
  const float* Wo = (const float*)d_in[7];
  const float* bo = (const float*)d_in[8];
  const float* de = (const float*)d_in[9];

  char* ws = (char*)d_ws;
  size_t off = 0;
  auto alloc = [&](size_t bytes) {
    size_t o = off;
    off += (bytes + 255) & ~(size_t)255;
    return o;
  };
  const size_t ACT = (size_t)BATCH * SEQ * HID * 2;  // 16 MB bf16
  const size_t WMT = (size_t)HID * HID * 2;          // 2 MB bf16
  short* hB  = (short*)(ws + alloc(ACT));
  short* wqB = (short*)(ws + alloc(WMT));
  short* wkB = (short*)(ws + alloc(WMT));
  short* wvB = (short*)(ws + alloc(WMT));
  short* woB = (short*)(ws + alloc(WMT));
  short* deB = (short*)(ws + alloc((size_t)NPOS * HD * 2));
  short* qB  = (short*)(ws + alloc(ACT));
  short* kB  = (short*)(ws + alloc(ACT));
  short* vB  = (short*)(ws + alloc(ACT));
  short* ctxB = hB;  // hB dead after QKV GEMMs; reuse for attention output

  auto cvt = [&](const float* in, short* outp, int n) {
    int n4 = n / 4;
    cvt_kernel<<<dim3((n4 + 255) / 256), dim3(256), 0, stream>>>(in, outp, n4);
  };
  cvt(hs, hB, BATCH * SEQ * HID);
  cvt(Wq, wqB, HID * HID);
  cvt(Wk, wkB, HID * HID);
  cvt(Wv, wvB, HID * HID);
  cvt(de, deB, NPOS * HD);
  cvt(Wo, woB, HID * HID);

  dim3 gg(BATCH * SEQ / 128, HID / 128), blk(256);
  gemm_nt<0><<<gg, blk, 0, stream>>>(hB, wqB, bq, qB, 0.125f);  // Q pre-scaled
  gemm_nt<0><<<gg, blk, 0, stream>>>(hB, wkB, bk, kB, 1.0f);
  gemm_nt<0><<<gg, blk, 0, stream>>>(hB, wvB, bv, vB, 1.0f);

  attn_kernel<<<dim3(SEQ / 64, NH, BATCH), blk, 0, stream>>>(qB, kB, vB, deB, ctxB);

  gemm_nt<1><<<gg, blk, 0, stream>>>(ctxB, woB, bo, d_out, 1.0f);
}

// Round 4
// 369.737 us; speedup vs baseline: 1.4672x; 1.4672x over previous
//
#include <hip/hip_runtime.h>
#include <stdint.h>

#define SEQ   2048
#define BATCH 4
#define NH    16
#define HD    64
#define HID   1024
#define NPOS  73

typedef __attribute__((ext_vector_type(8))) short short8;
typedef __attribute__((ext_vector_type(4))) short short4v;
typedef __attribute__((ext_vector_type(4))) float f32x4;

static __device__ __forceinline__ float bf2f(short s) {
  return __uint_as_float(((unsigned)(unsigned short)s) << 16);
}
static __device__ __forceinline__ short f2bf(float f) {
  unsigned u = __float_as_uint(f);
  u += 0x7fffu + ((u >> 16) & 1u);
  return (short)(u >> 16);
}

static __device__ __forceinline__ void gload_lds16(const void* g, void* lds) {
  __builtin_amdgcn_global_load_lds(
      (const __attribute__((address_space(1))) unsigned int*)g,
      (__attribute__((address_space(3))) unsigned int*)lds, 16, 0, 0);
}

__global__ __launch_bounds__(256) void cvt_kernel(const float* __restrict__ in,
                                                  short* __restrict__ out, int n4) {
  int i = blockIdx.x * 256 + threadIdx.x;
  if (i >= n4) return;
  f32x4 f = *(const f32x4*)(in + (long)i * 4);
  short4v o;
  o[0] = f2bf(f[0]); o[1] = f2bf(f[1]); o[2] = f2bf(f[2]); o[3] = f2bf(f[3]);
  *(short4v*)(out + (long)i * 4) = o;
}

// C = A * B^T + bias. A:[M,K] bf16 row-major, B:[N,K] bf16 row-major (NT).
// MODE 0: bf16 out scattered to [b,h,l,d] (row->(b,l), col->(h,d)), (acc+bias)*scale
// MODE 1: fp32 out [M,HID] row-major
// MODE 2: bf16 out scattered TRANSPOSED to [b,h,d,l] (for V^T)
template <int MODE>
__global__ __launch_bounds__(256) void gemm_nt(const short* __restrict__ A,
                                               const short* __restrict__ B,
                                               const float* __restrict__ bias,
                                               void* __restrict__ Cout, float scale) {
  __shared__ __align__(16) short As[128 * 32];
  __shared__ __align__(16) short Bs[128 * 32];
  const int K = HID;
  const f32x4 fzero = {0.f, 0.f, 0.f, 0.f};
  int t = threadIdx.x;
  int w = t >> 6, lane = t & 63;
  int wr = w >> 1, wc = w & 1;
  int g = lane >> 4, r = lane & 15;
  long tile_m = (long)blockIdx.x * 128;
  long tile_n = (long)blockIdx.y * 128;

  f32x4 acc[4][4];
#pragma unroll
  for (int m = 0; m < 4; ++m)
#pragma unroll
    for (int n = 0; n < 4; ++n) acc[m][n] = fzero;

  int e0 = w * 1024 + lane * 8;
  int e1 = e0 + 512;
  const short* A0 = A + (tile_m + (e0 >> 5)) * K + (e0 & 31);
  const short* A1 = A + (tile_m + (e1 >> 5)) * K + (e1 & 31);
  const short* B0 = B + (tile_n + (e0 >> 5)) * K + (e0 & 31);
  const short* B1 = B + (tile_n + (e1 >> 5)) * K + (e1 & 31);

  for (int k0 = 0; k0 < K; k0 += 32) {
    __syncthreads();
    gload_lds16(A0 + k0, &As[e0]);
    gload_lds16(A1 + k0, &As[e1]);
    gload_lds16(B0 + k0, &Bs[e0]);
    gload_lds16(B1 + k0, &Bs[e1]);
    __syncthreads();
    short8 af[4], bfr[4];
#pragma unroll
    for (int m = 0; m < 4; ++m)
      af[m] = *(const short8*)&As[(wr * 64 + m * 16 + r) * 32 + g * 8];
#pragma unroll
    for (int n = 0; n < 4; ++n)
      bfr[n] = *(const short8*)&Bs[(wc * 64 + n * 16 + r) * 32 + g * 8];
#pragma unroll
    for (int m = 0; m < 4; ++m)
#pragma unroll
      for (int n = 0; n < 4; ++n)
        acc[m][n] = __builtin_amdgcn_mfma_f32_16x16x32_bf16(af[m], bfr[n], acc[m][n], 0, 0, 0);
  }

#pragma unroll
  for (int m = 0; m < 4; ++m) {
    int row0 = (int)tile_m + wr * 64 + m * 16 + g * 4;
#pragma unroll
    for (int n = 0; n < 4; ++n) {
      int col = (int)tile_n + wc * 64 + n * 16 + r;
      float bs = bias[col];
#pragma unroll
      for (int j = 0; j < 4; ++j) {
        int row = row0 + j;
        float val = (acc[m][n][j] + bs) * scale;
        if (MODE == 0) {
          int b = row >> 11, l = row & (SEQ - 1);
          int hh = col >> 6, d = col & 63;
          ((short*)Cout)[(((long)(b * NH + hh) * SEQ + l) << 6) + d] = f2bf(val);
        } else if (MODE == 2) {
          int b = row >> 11, l = row & (SEQ - 1);
          int hh = col >> 6, d = col & 63;
          ((short*)Cout)[(((long)(b * NH + hh) * HD + d) << 11) + l] = f2bf(val);
        } else {
          ((float*)Cout)[(long)row * HID + col] = val;
        }
      }
    }
  }
}

// Flash attention with relative-position bias. XOR-swizzled LDS (T2):
// 16B slot index within each 128B row is XORed with (row&7); staged tiles get
// the swizzle via pre-swizzled per-lane GLOBAL source addresses (linear LDS dst).
// grid (SEQ/64, NH, BATCH), 256 threads. Q pre-scaled by 1/sqrt(HD).
// V input is pre-transposed [b,h,d,l].
__global__ __launch_bounds__(256) void attn_kernel(const short* __restrict__ Qg,
                                                   const short* __restrict__ Kg,
                                                   const short* __restrict__ Vg,
                                                   const short* __restrict__ DE,
                                                   short* __restrict__ ctx) {
  // arena: main loop {Ks 8K | Vt 8K | Pb 8K}; prologue alias {Qs 8K | Ds 9.3K}
  __shared__ __align__(16) char arena[24576];
  __shared__ float qd[64 * NPOS];  // per-row dist-bias dot products (18688 B)
  short* Ks = (short*)arena;
  short* Vt = (short*)(arena + 8192);
  short* Pbw = (short*)(arena + 16384);  // +w*1024 per wave
  short* Qs = (short*)arena;             // prologue alias
  short* Ds = (short*)(arena + 8192);    // prologue alias (spans into Pb region)

  const f32x4 fzero = {0.f, 0.f, 0.f, 0.f};
  int t = threadIdx.x;
  int w = t >> 6, lane = t & 63;
  int g = lane >> 4, r = lane & 15;
  int qt = blockIdx.x, h = blockIdx.y, b = blockIdx.z;
  int q0 = qt * 64;
  const short* Qp = Qg + ((long)(b * NH + h) * SEQ + q0) * HD;
  const short* Kp = Kg + (long)(b * NH + h) * SEQ * HD;
  const short* VTp = Vg + (long)(b * NH + h) * HD * SEQ;  // [d][l]

  int e0 = w * 1024 + lane * 8;
  int e1 = e0 + 512;

  // ---- prologue: stage Q (linear) + dist_emb (swizzled source) ----
  gload_lds16(Qp + e0, &Qs[e0]);
  gload_lds16(Qp + e1, &Qs[e1]);
#pragma unroll
  for (int i = 0; i < 3; ++i) {
    int s = i * 256 + t;  // 16B slot
    if (s < (NPOS * 64 / 8)) {
      int p = s >> 3;
      int sl = ((s & 7) ^ (p & 7)) * 8;
      gload_lds16(DE + p * 64 + sl, &Ds[s * 8]);
    }
  }
  __syncthreads();

  // qd[row][p] = sum_d Q[row][d] * dist_emb[p][d]  (scale already in Q)
  for (int idx = t; idx < 64 * NPOS; idx += 256) {
    int row = idx / NPOS, p = idx - row * NPOS;
    int px = (p & 7) << 3;
    float s = 0.f;
#pragma unroll
    for (int d0 = 0; d0 < 64; d0 += 8) {
      short8 a = *(const short8*)&Qs[row * 64 + d0];
      short8 bb = *(const short8*)&Ds[p * 64 + (d0 ^ px)];
#pragma unroll
      for (int j = 0; j < 8; ++j) s += bf2f(a[j]) * bf2f(bb[j]);
    }
    qd[idx] = s;
  }

  // hoist Q A-fragments (wave w owns rows w*16..w*16+15); Qs is linear
  short8 aq[2];
#pragma unroll
  for (int kb = 0; kb < 2; ++kb)
    aq[kb] = *(const short8*)&Qs[(w * 16 + r) * 64 + kb * 32 + g * 8];

  // swizzled staging source bases (row&7 == srow for both chunks)
  int srow = lane >> 3;                          // 0..7
  int ssl = ((lane & 7) ^ srow) * 8;             // pre-swizzled col chunk
  const short* K0 = Kp + (long)(w * 16 + srow) * HD + ssl;
  const short* K1 = Kp + (long)(w * 16 + 8 + srow) * HD + ssl;
  const short* V0 = VTp + (long)(w * 16 + srow) * SEQ + ssl;
  const short* V1 = VTp + (long)(w * 16 + 8 + srow) * SEQ + ssl;

  f32x4 o[4];
#pragma unroll
  for (int n = 0; n < 4; ++n) o[n] = fzero;
  float mrow[4] = {-1e30f, -1e30f, -1e30f, -1e30f};
  float lrow[4] = {0.f, 0.f, 0.f, 0.f};

  int rowl = w * 16 + g * 4;
  int rx = (r & 7) << 3;  // read-side swizzle for this lane
  short* Pw = Pbw + w * 1024;

  for (int kt = 0; kt < 32; ++kt) {
    int kv0 = kt * 64;
    __syncthreads();  // prior tile's LDS reads done (kt=0: qd/Qs/Ds reads done)
    gload_lds16(K0 + (long)kv0 * HD, &Ks[e0]);
    gload_lds16(K1 + (long)kv0 * HD, &Ks[e1]);
    gload_lds16(V0 + kv0, &Vt[e0]);
    gload_lds16(V1 + kv0, &Vt[e1]);
    __syncthreads();

    // S = Q K^T   (16 rows x 64 keys per wave), swizzled Ks reads
    f32x4 s[4];
#pragma unroll
    for (int n = 0; n < 4; ++n) s[n] = fzero;
#pragma unroll
    for (int kb = 0; kb < 2; ++kb)
#pragma unroll
      for (int n = 0; n < 4; ++n) {
        short8 bfr = *(const short8*)&Ks[(n * 16 + r) * 64 + ((kb * 32 + g * 8) ^ rx)];
        s[n] = __builtin_amdgcn_mfma_f32_16x16x32_bf16(aq[kb], bfr, s[n], 0, 0, 0);
      }

    // add relative bias, find row max
    float pm[4] = {-1e30f, -1e30f, -1e30f, -1e30f};
#pragma unroll
    for (int n = 0; n < 4; ++n) {
      int cg = kv0 + n * 16 + r;  // global key index
#pragma unroll
      for (int j = 0; j < 4; ++j) {
        int lq = q0 + rowl + j;
        int dist = cg - lq;
        dist = dist < -64 ? -64 : (dist > 8 ? 8 : dist);
        float val = s[n][j] + qd[(rowl + j) * NPOS + dist + 64];
        s[n][j] = val;
        pm[j] = fmaxf(pm[j], val);
      }
    }
#pragma unroll
    for (int off = 1; off < 16; off <<= 1)
#pragma unroll
      for (int j = 0; j < 4; ++j) pm[j] = fmaxf(pm[j], __shfl_xor(pm[j], off));

#pragma unroll
    for (int j = 0; j < 4; ++j) {
      float mn = fmaxf(mrow[j], pm[j]);
      float corr = __expf(mrow[j] - mn);
      mrow[j] = mn;
      lrow[j] *= corr;
#pragma unroll
      for (int n = 0; n < 4; ++n) o[n][j] *= corr;
    }
#pragma unroll
    for (int n = 0; n < 4; ++n)
#pragma unroll
      for (int j = 0; j < 4; ++j) {
        float p = __expf(s[n][j] - mrow[j]);
        lrow[j] += p;  // per-lane partial; reduced at end
        int prow = g * 4 + j;
        Pw[prow * 64 + ((n * 16 + r) ^ ((prow & 7) << 3))] = f2bf(p);
      }

    // O += P V   (same-wave LDS RAW: DS ops are in-order per wave)
#pragma unroll
    for (int kb = 0; kb < 2; ++kb) {
      short8 pa = *(const short8*)&Pw[r * 64 + ((kb * 32 + g * 8) ^ rx)];
#pragma unroll
      for (int n = 0; n < 4; ++n) {
        short8 vb = *(const short8*)&Vt[(n * 16 + r) * 64 + ((kb * 32 + g * 8) ^ rx)];
        o[n] = __builtin_amdgcn_mfma_f32_16x16x32_bf16(pa, vb, o[n], 0, 0, 0);
      }
    }
  }

#pragma unroll
  for (int off = 1; off < 16; off <<= 1)
#pragma unroll
    for (int j = 0; j < 4; ++j) lrow[j] += __shfl_xor(lrow[j], off);

#pragma unroll
  for (int n = 0; n < 4; ++n)
#pragma unroll
    for (int j = 0; j < 4; ++j) {
      int grow = b * SEQ + q0 + rowl + j;
      int gcol = h * HD + n * 16 + r;
      ctx[(long)grow * HID + gcol] = f2bf(o[n][j] / lrow[j]);
    }
}

extern "C" void kernel_launch(void* const* d_in, const int* in_sizes, int n_in,
                              void* d_out, int out_size, void* d_ws, size_t ws_size,
                              hipStream_t stream) {
  if (n_in < 10) return;
  const float* hs = (const float*)d_in[0];
  const float* Wq = (const float*)d_in[1];
  const float* bq = (const float*)d_in[2];
  const float* Wk = (const float*)d_in[3];
  const float* bk = (const float*)d_in[4];
  const float* Wv = (const float*)d_in[5];
  const float* bv = (const float*)d_in[6];
  const float* Wo = (const float*)d_in[7];
  const float* bo = (const float*)d_in[8];
  const float* de = (const float*)d_in[9];

  char* ws = (char*)d_ws;
  size_t off = 0;
  auto alloc = [&](size_t bytes) {
    size_t o = off;
    off += (bytes + 255) & ~(size_t)255;
    return o;
  };
  const size_t ACT = (size_t)BATCH * SEQ * HID * 2;  // 16 MB bf16
  const size_t WMT = (size_t)HID * HID * 2;          // 2 MB bf16
  short* hB  = (short*)(ws + alloc(ACT));
  short* wqB = (short*)(ws + alloc(WMT));
  short* wkB = (short*)(ws + alloc(WMT));
  short* wvB = (short*)(ws + alloc(WMT));
  short* woB = (short*)(ws + alloc(WMT));
  short* deB = (short*)(ws + alloc((size_t)NPOS * HD * 2));
  short* qB  = (short*)(ws + alloc(ACT));
  short* kB  = (short*)(ws + alloc(ACT));
  short* vB  = (short*)(ws + alloc(ACT));  // V^T layout [b,h,d,l]
  short* ctxB = hB;  // hB dead after QKV GEMMs; reuse for attention output

  auto cvt = [&](const float* in, short* outp, int n) {
    int n4 = n / 4;
    cvt_kernel<<<dim3((n4 + 255) / 256), dim3(256), 0, stream>>>(in, outp, n4);
  };
  cvt(hs, hB, BATCH * SEQ * HID);
  cvt(Wq, wqB, HID * HID);
  cvt(Wk, wkB, HID * HID);
  cvt(Wv, wvB, HID * HID);
  cvt(de, deB, NPOS * HD);
  cvt(Wo, woB, HID * HID);

  dim3 gg(BATCH * SEQ / 128, HID / 128), blk(256);
  gemm_nt<0><<<gg, blk, 0, stream>>>(hB, wqB, bq, qB, 0.125f);  // Q pre-scaled
  gemm_nt<0><<<gg, blk, 0, stream>>>(hB, wkB, bk, kB, 1.0f);
  gemm_nt<2><<<gg, blk, 0, stream>>>(hB, wvB, bv, vB, 1.0f);    // V transposed

  attn_kernel<<<dim3(SEQ / 64, NH, BATCH), blk, 0, stream>>>(qB, kB, vB, deB, ctxB);

  gemm_nt<1><<<gg, blk, 0, stream>>>(ctxB, woB, bo, d_out, 1.0f);
}

// Round 5
// 286.436 us; speedup vs baseline: 1.8939x; 1.2908x over previous
//
#include <hip/hip_runtime.h>
#include <stdint.h>

#define SEQ   2048
#define BATCH 4
#define NH    16
#define HD    64
#define HID   1024
#define NPOS  73

typedef __attribute__((ext_vector_type(8))) short short8;
typedef __attribute__((ext_vector_type(4))) short short4v;
typedef __attribute__((ext_vector_type(4))) float f32x4;

static __device__ __forceinline__ float bf2f(short s) {
  return __uint_as_float(((unsigned)(unsigned short)s) << 16);
}
static __device__ __forceinline__ short f2bf(float f) {
  unsigned u = __float_as_uint(f);
  u += 0x7fffu + ((u >> 16) & 1u);
  return (short)(u >> 16);
}
// packed f32x2 -> bf16x2 (RNE), no builtin on gfx950 -> inline asm
static __device__ __forceinline__ unsigned pkbf(float a, float b) {
  unsigned d;
  asm("v_cvt_pk_bf16_f32 %0, %1, %2" : "=v"(d) : "v"(a), "v"(b));
  return d;
}

static __device__ __forceinline__ void gload_lds16(const void* g, void* lds) {
  __builtin_amdgcn_global_load_lds(
      (const __attribute__((address_space(1))) unsigned int*)g,
      (__attribute__((address_space(3))) unsigned int*)lds, 16, 0, 0);
}

__global__ __launch_bounds__(256) void cvt_kernel(const float* __restrict__ in,
                                                  short* __restrict__ out, int n4) {
  int i = blockIdx.x * 256 + threadIdx.x;
  if (i >= n4) return;
  f32x4 f = *(const f32x4*)(in + (long)i * 4);
  short4v o;
  o[0] = f2bf(f[0]); o[1] = f2bf(f[1]); o[2] = f2bf(f[2]); o[3] = f2bf(f[3]);
  *(short4v*)(out + (long)i * 4) = o;
}

// C = A * B^T + bias. A:[M,K] bf16 row-major, B:[N,K] bf16 row-major (NT).
// MODE 0: bf16 out scattered to [b,h,l,d]; MODE 1: fp32 out [M,HID];
// MODE 2: bf16 out scattered transposed to [b,h,d,l] (V^T)
template <int MODE>
__global__ __launch_bounds__(256) void gemm_nt(const short* __restrict__ A,
                                               const short* __restrict__ B,
                                               const float* __restrict__ bias,
                                               void* __restrict__ Cout, float scale) {
  __shared__ __align__(16) short As[128 * 32];
  __shared__ __align__(16) short Bs[128 * 32];
  const int K = HID;
  const f32x4 fzero = {0.f, 0.f, 0.f, 0.f};
  int t = threadIdx.x;
  int w = t >> 6, lane = t & 63;
  int wr = w >> 1, wc = w & 1;
  int g = lane >> 4, r = lane & 15;
  long tile_m = (long)blockIdx.x * 128;
  long tile_n = (long)blockIdx.y * 128;

  f32x4 acc[4][4];
#pragma unroll
  for (int m = 0; m < 4; ++m)
#pragma unroll
    for (int n = 0; n < 4; ++n) acc[m][n] = fzero;

  int e0 = w * 1024 + lane * 8;
  int e1 = e0 + 512;
  const short* A0 = A + (tile_m + (e0 >> 5)) * K + (e0 & 31);
  const short* A1 = A + (tile_m + (e1 >> 5)) * K + (e1 & 31);
  const short* B0 = B + (tile_n + (e0 >> 5)) * K + (e0 & 31);
  const short* B1 = B + (tile_n + (e1 >> 5)) * K + (e1 & 31);

  for (int k0 = 0; k0 < K; k0 += 32) {
    __syncthreads();
    gload_lds16(A0 + k0, &As[e0]);
    gload_lds16(A1 + k0, &As[e1]);
    gload_lds16(B0 + k0, &Bs[e0]);
    gload_lds16(B1 + k0, &Bs[e1]);
    __syncthreads();
    short8 af[4], bfr[4];
#pragma unroll
    for (int m = 0; m < 4; ++m)
      af[m] = *(const short8*)&As[(wr * 64 + m * 16 + r) * 32 + g * 8];
#pragma unroll
    for (int n = 0; n < 4; ++n)
      bfr[n] = *(const short8*)&Bs[(wc * 64 + n * 16 + r) * 32 + g * 8];
#pragma unroll
    for (int m = 0; m < 4; ++m)
#pragma unroll
      for (int n = 0; n < 4; ++n)
        acc[m][n] = __builtin_amdgcn_mfma_f32_16x16x32_bf16(af[m], bfr[n], acc[m][n], 0, 0, 0);
  }

#pragma unroll
  for (int m = 0; m < 4; ++m) {
    int row0 = (int)tile_m + wr * 64 + m * 16 + g * 4;
#pragma unroll
    for (int n = 0; n < 4; ++n) {
      int col = (int)tile_n + wc * 64 + n * 16 + r;
      float bs = bias[col];
#pragma unroll
      for (int j = 0; j < 4; ++j) {
        int row = row0 + j;
        float val = (acc[m][n][j] + bs) * scale;
        if (MODE == 0) {
          int b = row >> 11, l = row & (SEQ - 1);
          int hh = col >> 6, d = col & 63;
          ((short*)Cout)[(((long)(b * NH + hh) * SEQ + l) << 6) + d] = f2bf(val);
        } else if (MODE == 2) {
          int b = row >> 11, l = row & (SEQ - 1);
          int hh = col >> 6, d = col & 63;
          ((short*)Cout)[(((long)(b * NH + hh) * HD + d) << 11) + l] = f2bf(val);
        } else {
          ((float*)Cout)[(long)row * HID + col] = val;
        }
      }
    }
  }
}

// Flash attention, swapped-operand softmax (S^T = K·Q^T so each lane owns one
// q-row = lane&15 per sub-tile; softmax is lane-local, P feeds PV's B-fragment
// straight from registers via v_cvt_pk_bf16_f32 — no P LDS round-trip).
// Q-block 128 (4 waves x 32 q, K/V frags shared across 2 q-sub-tiles).
// grid (SEQ/128, NH, BATCH), 256 threads. Q pre-scaled by 1/sqrt(HD).
// V input pre-transposed [b,h,d,l]. K/V LDS XOR-swizzled on 16B slots
// (pre-swizzled global source, linear gload_lds dest).
__global__ __launch_bounds__(256, 3) void attn_kernel(const short* __restrict__ Qg,
                                                      const short* __restrict__ Kg,
                                                      const short* __restrict__ Vg,
                                                      const short* __restrict__ DE,
                                                      short* __restrict__ ctx) {
  // main loop: Ks[64*64]@0 (8K) | Vt[64*64]@8192 (8K); prologue alias:
  // Qs[128*64]@0 (16K), Ds[73*64]@16384 (9344) -> arena 25728
  __shared__ __align__(16) char arena[25728];
  __shared__ __align__(16) short qd2[128 * NPOS];  // bf16 per-row dist-bias dots

  short* Ks = (short*)arena;
  short* Vt = (short*)(arena + 8192);
  short* Qs = (short*)arena;             // prologue alias (16K)
  short* Ds = (short*)(arena + 16384);   // prologue alias

  const f32x4 fzero = {0.f, 0.f, 0.f, 0.f};
  int t = threadIdx.x;
  int w = t >> 6, lane = t & 63;
  int g = lane >> 4, r = lane & 15;
  int qt = blockIdx.x, h = blockIdx.y, b = blockIdx.z;
  int q0 = qt * 128;
  const short* Qp = Qg + ((long)(b * NH + h) * SEQ + q0) * HD;
  const short* Kp = Kg + (long)(b * NH + h) * SEQ * HD;
  const short* VTp = Vg + (long)(b * NH + h) * HD * SEQ;  // [d][l]

  // ---- prologue: stage Q (linear, 16K) + dist_emb (swizzled source) ----
#pragma unroll
  for (int c = 0; c < 8; ++c)
    gload_lds16(Qp + c * 2048 + t * 8, &Qs[c * 2048 + t * 8]);
#pragma unroll
  for (int i = 0; i < 3; ++i) {
    int sl = i * 256 + t;  // 16B slot
    if (sl < (NPOS * 64 / 8)) {
      int p = sl >> 3;
      int cc = ((sl & 7) ^ (p & 7)) * 8;
      gload_lds16(DE + p * 64 + cc, &Ds[sl * 8]);
    }
  }
  __syncthreads();

  // qd2[row][p] = sum_d Q[row][d] * dist_emb[p][d]  (scale already in Q)
  for (int idx = t; idx < 128 * NPOS; idx += 256) {
    int row = idx / NPOS, p = idx - row * NPOS;
    int px = (p & 7) << 3;
    float acc = 0.f;
#pragma unroll
    for (int d0 = 0; d0 < 64; d0 += 8) {
      short8 a = *(const short8*)&Qs[row * 64 + d0];
      short8 bb = *(const short8*)&Ds[p * 64 + (d0 ^ px)];
#pragma unroll
      for (int j = 0; j < 8; ++j) acc += bf2f(a[j]) * bf2f(bb[j]);
    }
    qd2[idx] = f2bf(acc);
  }

  // hoist Q B-fragments: wave w owns q rows w*32..w*32+31, sub-tiles hq=0,1
  short8 aq[2][2];
#pragma unroll
  for (int hq = 0; hq < 2; ++hq)
#pragma unroll
    for (int kb = 0; kb < 2; ++kb)
      aq[hq][kb] = *(const short8*)&Qs[(w * 32 + hq * 16 + r) * 64 + kb * 32 + g * 8];
  __syncthreads();  // qd2 visible; Qs/Ds reads done before Ks/Vt staging

  int qb0 = (w * 32 + r) * NPOS;
  int qb1 = qb0 + 16 * NPOS;
  float bl0 = bf2f(qd2[qb0]), br0 = bf2f(qd2[qb0 + 72]);
  float bl1 = bf2f(qd2[qb1]), br1 = bf2f(qd2[qb1 + 72]);

  // staging sources (16B-slot XOR swizzle via global address)
  int srow = lane >> 3;
  int ssl = ((lane & 7) ^ srow) * 8;
  const short* K0 = Kp + (long)(w * 16 + srow) * HD + ssl;
  const short* K1 = Kp + (long)(w * 16 + 8 + srow) * HD + ssl;
  const short* V0 = VTp + (long)(w * 16 + srow) * SEQ + ssl;
  const short* V1 = VTp + (long)(w * 16 + 8 + srow) * SEQ + ssl;
  int e0 = w * 1024 + lane * 8;
  int e1 = e0 + 512;
  int rx = (r & 7) << 3;
  int Lw = q0 + w * 32;

  f32x4 o0[4], o1[4];
#pragma unroll
  for (int n = 0; n < 4; ++n) { o0[n] = fzero; o1[n] = fzero; }
  float m0 = -1e30f, m1 = -1e30f, l0 = 0.f, l1 = 0.f;

  union U8 { unsigned u[4]; short8 v; };

  auto softmax_step = [&](f32x4 (&sx)[4], float& m, float& l, f32x4 (&ox)[4]) {
    float pm = sx[0][0];
#pragma unroll
    for (int n = 0; n < 4; ++n)
#pragma unroll
      for (int j = 0; j < 4; ++j) pm = fmaxf(pm, sx[n][j]);
    pm = fmaxf(pm, __shfl_xor(pm, 16));
    pm = fmaxf(pm, __shfl_xor(pm, 32));
    if (__any(pm > m + 8.f)) {  // defer-max (T13)
      float mn = fmaxf(m, pm);
      float corr = __expf(m - mn);
      m = mn;
      l *= corr;
#pragma unroll
      for (int n = 0; n < 4; ++n)
#pragma unroll
        for (int j = 0; j < 4; ++j) ox[n][j] *= corr;
    }
#pragma unroll
    for (int n = 0; n < 4; ++n)
#pragma unroll
      for (int j = 0; j < 4; ++j) {
        float p = __expf(sx[n][j] - m);
        l += p;
        sx[n][j] = p;
      }
  };

  for (int kt = 0; kt < 32; ++kt) {
    int kv0 = kt * 64;
    __syncthreads();  // prior tile's LDS reads done
    gload_lds16(K0 + (long)kv0 * HD, &Ks[e0]);
    gload_lds16(K1 + (long)kv0 * HD, &Ks[e1]);
    gload_lds16(V0 + kv0, &Vt[e0]);
    gload_lds16(V1 + kv0, &Vt[e1]);
    __syncthreads();

    // S^T = K Q^T: C rows = keys (n*16+g*4+j), col = q (r). K-frag shared hq.
    f32x4 s0[4], s1[4];
#pragma unroll
    for (int n = 0; n < 4; ++n) { s0[n] = fzero; s1[n] = fzero; }
#pragma unroll
    for (int kb = 0; kb < 2; ++kb)
#pragma unroll
      for (int n = 0; n < 4; ++n) {
        short8 kfr = *(const short8*)&Ks[(n * 16 + r) * 64 + ((kb * 32 + g * 8) ^ rx)];
        s0[n] = __builtin_amdgcn_mfma_f32_16x16x32_bf16(kfr, aq[0][kb], s0[n], 0, 0, 0);
        s1[n] = __builtin_amdgcn_mfma_f32_16x16x32_bf16(kfr, aq[1][kb], s1[n], 0, 0, 0);
      }

    // relative bias: wave-uniform clamped fast path (29/32 tiles)
    bool allL = (kv0 + 63) <= (Lw - 64);
    bool allR = kv0 >= (Lw + 31 + 8);
    if (allL || allR) {
      float b0 = allL ? bl0 : br0;
      float b1 = allL ? bl1 : br1;
#pragma unroll
      for (int n = 0; n < 4; ++n)
#pragma unroll
        for (int j = 0; j < 4; ++j) { s0[n][j] += b0; s1[n][j] += b1; }
    } else {
      int lq = q0 + w * 32 + r;
#pragma unroll
      for (int n = 0; n < 4; ++n) {
        int key = kv0 + n * 16 + g * 4;
#pragma unroll
        for (int j = 0; j < 4; ++j) {
          int d0i = key + j - lq;
          d0i = d0i < -64 ? -64 : (d0i > 8 ? 8 : d0i);
          int d1i = key + j - lq - 16;
          d1i = d1i < -64 ? -64 : (d1i > 8 ? 8 : d1i);
          s0[n][j] += bf2f(qd2[qb0 + d0i + 64]);
          s1[n][j] += bf2f(qd2[qb1 + d1i + 64]);
        }
      }
    }

    softmax_step(s0, m0, l0, o0);
    softmax_step(s1, m1, l1, o1);

    // O^T += V^T P^T : A = V^T-frag (k-permuted to match), B = P from regs
#pragma unroll
    for (int w32 = 0; w32 < 2; ++w32) {
      U8 pb0, pb1;
      pb0.u[0] = pkbf(s0[2 * w32][0], s0[2 * w32][1]);
      pb0.u[1] = pkbf(s0[2 * w32][2], s0[2 * w32][3]);
      pb0.u[2] = pkbf(s0[2 * w32 + 1][0], s0[2 * w32 + 1][1]);
      pb0.u[3] = pkbf(s0[2 * w32 + 1][2], s0[2 * w32 + 1][3]);
      pb1.u[0] = pkbf(s1[2 * w32][0], s1[2 * w32][1]);
      pb1.u[1] = pkbf(s1[2 * w32][2], s1[2 * w32][3]);
      pb1.u[2] = pkbf(s1[2 * w32 + 1][0], s1[2 * w32 + 1][1]);
      pb1.u[3] = pkbf(s1[2 * w32 + 1][2], s1[2 * w32 + 1][3]);
      // V^T cols w32*32 + {g*4..+3, 16+g*4..+3}, 16B-slot swizzled by row
      int cA = (((w32 * 4 + (g >> 1)) ^ (r & 7)) << 3) + ((g & 1) * 4);
      int cB = (((w32 * 4 + 2 + (g >> 1)) ^ (r & 7)) << 3) + ((g & 1) * 4);
#pragma unroll
      for (int n = 0; n < 4; ++n) {
        const short* vrow = &Vt[(n * 16 + r) * 64];
        short4v va_ = *(const short4v*)(vrow + cA);
        short4v vb_ = *(const short4v*)(vrow + cB);
        short8 v8;
        v8[0] = va_[0]; v8[1] = va_[1]; v8[2] = va_[2]; v8[3] = va_[3];
        v8[4] = vb_[0]; v8[5] = vb_[1]; v8[6] = vb_[2]; v8[7] = vb_[3];
        o0[n] = __builtin_amdgcn_mfma_f32_16x16x32_bf16(v8, pb0.v, o0[n], 0, 0, 0);
        o1[n] = __builtin_amdgcn_mfma_f32_16x16x32_bf16(v8, pb1.v, o1[n], 0, 0, 0);
      }
    }
  }

  // epilogue: reduce l across the 4 lanes sharing q, normalize, pack, store
  l0 += __shfl_xor(l0, 16); l0 += __shfl_xor(l0, 32);
  l1 += __shfl_xor(l1, 16); l1 += __shfl_xor(l1, 32);
  float inv0 = 1.f / l0, inv1 = 1.f / l1;
  long grow0 = (long)(b * SEQ + q0 + w * 32 + r);
  long grow1 = grow0 + 16;
#pragma unroll
  for (int n = 0; n < 4; ++n) {
    uint2 v0, v1;
    v0.x = pkbf(o0[n][0] * inv0, o0[n][1] * inv0);
    v0.y = pkbf(o0[n][2] * inv0, o0[n][3] * inv0);
    v1.x = pkbf(o1[n][0] * inv1, o1[n][1] * inv1);
    v1.y = pkbf(o1[n][2] * inv1, o1[n][3] * inv1);
    *(uint2*)&ctx[grow0 * HID + h * 64 + n * 16 + g * 4] = v0;
    *(uint2*)&ctx[grow1 * HID + h * 64 + n * 16 + g * 4] = v1;
  }
}

extern "C" void kernel_launch(void* const* d_in, const int* in_sizes, int n_in,
                              void* d_out, int out_size, void* d_ws, size_t ws_size,
                              hipStream_t stream) {
  if (n_in < 10) return;
  const float* hs = (const float*)d_in[0];
  const float* Wq = (const float*)d_in[1];
  const float* bq = (const float*)d_in[2];
  const float* Wk = (const float*)d_in[3];
  const float* bk = (const float*)d_in[4];
  const float* Wv = (const float*)d_in[5];
  const float* bv = (const float*)d_in[6];
  const float* Wo = (const float*)d_in[7];
  const float* bo = (const float*)d_in[8];
  const float* de = (const float*)d_in[9];

  char* ws = (char*)d_ws;
  size_t off = 0;
  auto alloc = [&](size_t bytes) {
    size_t o = off;
    off += (bytes + 255) & ~(size_t)255;
    return o;
  };
  const size_t ACT = (size_t)BATCH * SEQ * HID * 2;  // 16 MB bf16
  const size_t WMT = (size_t)HID * HID * 2;          // 2 MB bf16
  short* hB  = (short*)(ws + alloc(ACT));
  short* wqB = (short*)(ws + alloc(WMT));
  short* wkB = (short*)(ws + alloc(WMT));
  short* wvB = (short*)(ws + alloc(WMT));
  short* woB = (short*)(ws + alloc(WMT));
  short* deB = (short*)(ws + alloc((size_t)NPOS * HD * 2));
  short* qB  = (short*)(ws + alloc(ACT));
  short* kB  = (short*)(ws + alloc(ACT));
  short* vB  = (short*)(ws + alloc(ACT));  // V^T layout [b,h,d,l]
  short* ctxB = hB;  // hB dead after QKV GEMMs; reuse for attention output

  auto cvt = [&](const float* in, short* outp, int n) {
    int n4 = n / 4;
    cvt_kernel<<<dim3((n4 + 255) / 256), dim3(256), 0, stream>>>(in, outp, n4);
  };
  cvt(hs, hB, BATCH * SEQ * HID);
  cvt(Wq, wqB, HID * HID);
  cvt(Wk, wkB, HID * HID);
  cvt(Wv, wvB, HID * HID);
  cvt(de, deB, NPOS * HD);
  cvt(Wo, woB, HID * HID);

  dim3 gg(BATCH * SEQ / 128, HID / 128), blk(256);
  gemm_nt<0><<<gg, blk, 0, stream>>>(hB, wqB, bq, qB, 0.125f);  // Q pre-scaled
  gemm_nt<0><<<gg, blk, 0, stream>>>(hB, wkB, bk, kB, 1.0f);
  gemm_nt<2><<<gg, blk, 0, stream>>>(hB, wvB, bv, vB, 1.0f);    // V transposed

  attn_kernel<<<dim3(SEQ / 128, NH, BATCH), blk, 0, stream>>>(qB, kB, vB, deB, ctxB);

  gemm_nt<1><<<gg, blk, 0, stream>>>(ctxB, woB, bo, d_out, 1.0f);
}